// Round 10
// baseline (220.086 us; speedup 1.0000x reference)
//
#include <hip/hip_runtime.h>

#define N_ATOMS 100000
#define N_EDGES 625000
#define N_MOL   1000
#define EMB_ATOM 256
#define EMB_EDGE 128

typedef float f32x4 __attribute__((ext_vector_type(4)));

__device__ __forceinline__ float dot4(f32x4 a, f32x4 b) {
    return a.x * b.x + a.y * b.y + a.z * b.z + a.w * b.w;
}

// Vectorized zero of d_out (301000 floats = 75250 f32x4 exactly).
__global__ __launch_bounds__(256) void zero_kernel(f32x4* __restrict__ p, int n4)
{
    const int i = blockIdx.x * blockDim.x + threadIdx.x;
    if (i < n4) p[i] = (f32x4)(0.f, 0.f, 0.f, 0.f);
}

// ---- K1: pure streaming edge dot-products (NO atomics) ----
// R8's proven shape: 8 lanes per edge row, 2 groups -> 16 edges/wave,
// 128B/thread in flight. After the 3-stage butterfly each slot's sub==0
// lane stores s+bias to ws[e] (8 consecutive floats per wave per group).
#define FWAVES  ((N_EDGES + 15) / 16)            // 39063
#define FBLOCKS ((FWAVES + 3) / 4)               // 9767

__global__ __launch_bounds__(256) void edge_dot_kernel(
    const float* __restrict__ h_forces,
    const float* __restrict__ W_forces,
    const float* __restrict__ b_forces,
    float*       __restrict__ s_ws)
{
    const int lane = threadIdx.x & 63;
    const int w    = blockIdx.x * 4 + (threadIdx.x >> 6);
    const int slot = lane >> 3;      // 0..7 : edge slot within wave
    const int sub  = lane & 7;       // 0..7 : position within edge row

    const f32x4* wf   = reinterpret_cast<const f32x4*>(W_forces);
    const f32x4* base = reinterpret_cast<const f32x4*>(h_forces); // row = 32 f32x4

    f32x4 b0 = wf[sub + 0];
    f32x4 b1 = wf[sub + 8];
    f32x4 b2 = wf[sub + 16];
    f32x4 b3 = wf[sub + 24];
    const float bias = b_forces[0];

    #pragma unroll
    for (int g = 0; g < 2; ++g) {
        const int e = w * 16 + g * 8 + slot;
        float s = 0.f;
        if (e < N_EDGES) {
            const f32x4* row = base + (size_t)e * 32;
            f32x4 a0 = __builtin_nontemporal_load(row + sub + 0);
            f32x4 a1 = __builtin_nontemporal_load(row + sub + 8);
            f32x4 a2 = __builtin_nontemporal_load(row + sub + 16);
            f32x4 a3 = __builtin_nontemporal_load(row + sub + 24);
            s = dot4(a0, b0) + dot4(a1, b1) + dot4(a2, b2) + dot4(a3, b3);
        }
        s += __shfl_xor(s, 1, 64);
        s += __shfl_xor(s, 2, 64);
        s += __shfl_xor(s, 4, 64);
        if (e < N_EDGES && sub == 0) s_ws[e] = s + bias;
    }
}

// ---- K2: scatter (atomics) + energy, fused ----
// Blocks [0, SBLOCKS): one thread per edge -> read s, idx, V_st,
//   3 atomicAdds into force_out (consecutive addresses t*3..t*3+2).
// Blocks [SBLOCKS, SBLOCKS+EBLOCKS): R8's energy section unchanged.
#define SBLOCKS ((N_EDGES + 255) / 256)          // 2442
#define EWAVES  (N_ATOMS / 8)                    // 12500 (exact)
#define EBLOCKS (EWAVES / 4)                     // 3125

__global__ __launch_bounds__(256) void scatter_energy_kernel(
    const float* __restrict__ s_ws,
    const float* __restrict__ V_st,
    const int*   __restrict__ idx_t,
    const float* __restrict__ h_energy,
    const int*   __restrict__ batch_idx,
    const float* __restrict__ W_energy,
    float*       __restrict__ y_out,
    float*       __restrict__ force_out)
{
    if (blockIdx.x < SBLOCKS) {
        // ---------------- scatter ----------------
        const int e = blockIdx.x * 256 + threadIdx.x;
        if (e >= N_EDGES) return;
        const float s  = s_ws[e];
        const int   t  = idx_t[e];
        const float v0 = V_st[(size_t)e * 3 + 0];
        const float v1 = V_st[(size_t)e * 3 + 1];
        const float v2 = V_st[(size_t)e * 3 + 2];
        float* dst = force_out + (size_t)t * 3;
        atomicAdd(dst + 0, s * v0);
        atomicAdd(dst + 1, s * v1);
        atomicAdd(dst + 2, s * v2);
    } else {
        // ---------------- energy (R8 shape) ----------------
        const int lane = threadIdx.x & 63;
        const int w    = (blockIdx.x - SBLOCKS) * 4 + (threadIdx.x >> 6);
        const int slot = lane >> 4;      // 0..3 : atom slot
        const int sub  = lane & 15;      // 0..15: position within atom row

        const f32x4* we   = reinterpret_cast<const f32x4*>(W_energy);
        const f32x4* base = reinterpret_cast<const f32x4*>(h_energy); // row = 64 f32x4

        f32x4 b0 = we[sub + 0];
        f32x4 b1 = we[sub + 16];
        f32x4 b2 = we[sub + 32];
        f32x4 b3 = we[sub + 48];

        #pragma unroll
        for (int g = 0; g < 2; ++g) {
            const int a = w * 8 + g * 4 + slot;   // < 100000 always (12500 waves exact)
            const f32x4* row = base + (size_t)a * 64;
            f32x4 a0 = __builtin_nontemporal_load(row + sub + 0);
            f32x4 a1 = __builtin_nontemporal_load(row + sub + 16);
            f32x4 a2 = __builtin_nontemporal_load(row + sub + 32);
            f32x4 a3 = __builtin_nontemporal_load(row + sub + 48);
            float s = dot4(a0, b0) + dot4(a1, b1) + dot4(a2, b2) + dot4(a3, b3);

            s += __shfl_xor(s, 1, 64);
            s += __shfl_xor(s, 2, 64);
            s += __shfl_xor(s, 4, 64);
            s += __shfl_xor(s, 8, 64);

            if (sub == 0) atomicAdd(&y_out[batch_idx[a]], s);
        }
    }
}

extern "C" void kernel_launch(void* const* d_in, const int* in_sizes, int n_in,
                              void* d_out, int out_size, void* d_ws, size_t ws_size,
                              hipStream_t stream) {
    const float* h_energy  = (const float*)d_in[0];
    const float* h_forces  = (const float*)d_in[1];
    const float* V_st      = (const float*)d_in[2];
    const int*   idx_t     = (const int*)d_in[3];
    const int*   batch_idx = (const int*)d_in[4];
    const float* W_energy  = (const float*)d_in[5];
    const float* W_forces  = (const float*)d_in[6];
    const float* b_forces  = (const float*)d_in[7];

    float* y_out     = (float*)d_out;            // N_MOL floats
    float* force_out = (float*)d_out + N_MOL;    // N_ATOMS*3 floats
    float* s_ws      = (float*)d_ws;             // N_EDGES floats (2.5 MB)

    // Zero d_out (atomic accumulation needs zeroed output each call).
    const int n4 = out_size / 4;                 // 75250 exactly
    zero_kernel<<<(n4 + 255) / 256, 256, 0, stream>>>((f32x4*)d_out, n4);

    // K1: pure-stream edge dots -> s_ws. 9767 blocks.
    edge_dot_kernel<<<FBLOCKS, 256, 0, stream>>>(h_forces, W_forces, b_forces, s_ws);

    // K2: scatter (2442 blocks) + energy (3125 blocks).
    scatter_energy_kernel<<<SBLOCKS + EBLOCKS, 256, 0, stream>>>(
        s_ws, V_st, idx_t, h_energy, batch_idx, W_energy, y_out, force_out);
}

// Round 11
// 99.378 us; speedup vs baseline: 2.2146x; 2.2146x over previous
//
#include <hip/hip_runtime.h>

#define N_ATOMS 100000
#define N_EDGES 625000
#define N_MOL   1000
#define EMB_ATOM 256
#define EMB_EDGE 128

typedef float f32x4 __attribute__((ext_vector_type(4)));

__device__ __forceinline__ float dot4(f32x4 a, f32x4 b) {
    return a.x * b.x + a.y * b.y + a.z * b.z + a.w * b.w;
}

// ---- workspace layout (floats) ----
// rep_y : 4 replicas x 1024   at ws[0 .. 4096)
// rep_f : 4 replicas x 300000 at ws[4096 .. 1204096)
#define REP      4
#define YREP_STR 1024
#define FREP_OFF 4096
#define FREP_STR 300000
#define WS_FLOATS (FREP_OFF + REP * FREP_STR)    // 1204096 (= 301024 f32x4)

// Zero the replica accumulators (not d_out - merge overwrites d_out fully).
__global__ __launch_bounds__(256) void zero_kernel(f32x4* __restrict__ p, int n4)
{
    const int i = blockIdx.x * blockDim.x + threadIdx.x;
    if (i < n4) p[i] = (f32x4)(0.f, 0.f, 0.f, 0.f);
}

// Merge replicas into d_out. Elements 0..249 are y (1000 floats), elements
// 250..75249 are force (300000 floats).
__global__ __launch_bounds__(256) void merge_kernel(
    const float* __restrict__ ws, float* __restrict__ out)
{
    const int i = blockIdx.x * blockDim.x + threadIdx.x;
    if (i >= 250 + 75000) return;
    const f32x4* w4 = reinterpret_cast<const f32x4*>(ws);
    f32x4*       o4 = reinterpret_cast<f32x4*>(out);
    if (i < 250) {
        f32x4 s = w4[i] + w4[i + (YREP_STR/4)] + w4[i + 2*(YREP_STR/4)] + w4[i + 3*(YREP_STR/4)];
        o4[i] = s;
    } else {
        const int j = i - 250;               // force f32x4 index
        const f32x4* f4 = w4 + FREP_OFF/4;
        f32x4 s = f4[j] + f4[j + FREP_STR/4] + f4[j + 2*(FREP_STR/4)] + f4[j + 3*(FREP_STR/4)];
        o4[i] = s;                           // out offset 250 f32x4 = 1000 floats
    }
}

// Fused persistent kernel. Blocks [0, FPBLOCKS): forces, grid-stride over
// 16-edge tiles (R8 shape: 8 lanes/edge, 2 groups, 128B/thread in flight).
// Blocks [FPBLOCKS, FPBLOCKS+EPBLOCKS): energy, grid-stride over 8-atom
// tiles (16 lanes/atom, 2 groups). Atomics go to replica (wslot&3) in ws.
#define FTILES  ((N_EDGES + 15) / 16)            // 39063
#define FPBLOCKS 2048                            // 8192 wave-slots, ~4.8 tiles each
#define ETILES  (N_ATOMS / 8)                    // 12500 exact
#define EPBLOCKS 512                             // 2048 wave-slots, ~6.1 tiles each

__global__ __launch_bounds__(256) void fused_kernel(
    const float* __restrict__ h_energy,
    const float* __restrict__ h_forces,
    const float* __restrict__ V_st,
    const int*   __restrict__ idx_t,
    const int*   __restrict__ batch_idx,
    const float* __restrict__ W_energy,
    const float* __restrict__ W_forces,
    const float* __restrict__ b_forces,
    float*       __restrict__ ws)
{
    const int lane = threadIdx.x & 63;

    if (blockIdx.x < FPBLOCKS) {
        // ---------------- forces ----------------
        const int wslot = blockIdx.x * 4 + (threadIdx.x >> 6);
        const int slot  = lane >> 3;     // 0..7 : edge slot
        const int sub   = lane & 7;      // 0..7 : position within edge row

        const f32x4* wf   = reinterpret_cast<const f32x4*>(W_forces);
        const f32x4* base = reinterpret_cast<const f32x4*>(h_forces); // row = 32 f32x4
        float* frep = ws + FREP_OFF + (wslot & (REP-1)) * FREP_STR;

        f32x4 b0 = wf[sub + 0];
        f32x4 b1 = wf[sub + 8];
        f32x4 b2 = wf[sub + 16];
        f32x4 b3 = wf[sub + 24];
        const float bias = b_forces[0];

        for (int tile = wslot; tile < FTILES; tile += FPBLOCKS * 4) {
            #pragma unroll
            for (int g = 0; g < 2; ++g) {
                const int e = tile * 16 + g * 8 + slot;
                float s = 0.f;
                if (e < N_EDGES) {
                    const f32x4* row = base + (size_t)e * 32;
                    f32x4 a0 = __builtin_nontemporal_load(row + sub + 0);
                    f32x4 a1 = __builtin_nontemporal_load(row + sub + 8);
                    f32x4 a2 = __builtin_nontemporal_load(row + sub + 16);
                    f32x4 a3 = __builtin_nontemporal_load(row + sub + 24);
                    s = dot4(a0, b0) + dot4(a1, b1) + dot4(a2, b2) + dot4(a3, b3);
                }
                s += __shfl_xor(s, 1, 64);
                s += __shfl_xor(s, 2, 64);
                s += __shfl_xor(s, 4, 64);
                if (e < N_EDGES && sub < 3) {
                    const int   t = idx_t[e];
                    const float v = V_st[(size_t)e * 3 + sub];
                    atomicAdd(&frep[(size_t)t * 3 + sub], (s + bias) * v);
                }
            }
        }
    } else if (blockIdx.x < FPBLOCKS + EPBLOCKS) {
        // ---------------- energy ----------------
        const int wslot = (blockIdx.x - FPBLOCKS) * 4 + (threadIdx.x >> 6);
        const int slot  = lane >> 4;     // 0..3 : atom slot
        const int sub   = lane & 15;     // 0..15: position within atom row

        const f32x4* we   = reinterpret_cast<const f32x4*>(W_energy);
        const f32x4* base = reinterpret_cast<const f32x4*>(h_energy); // row = 64 f32x4
        float* yrep = ws + (wslot & (REP-1)) * YREP_STR;

        f32x4 b0 = we[sub + 0];
        f32x4 b1 = we[sub + 16];
        f32x4 b2 = we[sub + 32];
        f32x4 b3 = we[sub + 48];

        for (int tile = wslot; tile < ETILES; tile += EPBLOCKS * 4) {
            #pragma unroll
            for (int g = 0; g < 2; ++g) {
                const int a = tile * 8 + g * 4 + slot;   // < 100000 exact
                const f32x4* row = base + (size_t)a * 64;
                f32x4 a0 = __builtin_nontemporal_load(row + sub + 0);
                f32x4 a1 = __builtin_nontemporal_load(row + sub + 16);
                f32x4 a2 = __builtin_nontemporal_load(row + sub + 32);
                f32x4 a3 = __builtin_nontemporal_load(row + sub + 48);
                float s = dot4(a0, b0) + dot4(a1, b1) + dot4(a2, b2) + dot4(a3, b3);

                s += __shfl_xor(s, 1, 64);
                s += __shfl_xor(s, 2, 64);
                s += __shfl_xor(s, 4, 64);
                s += __shfl_xor(s, 8, 64);

                if (sub == 0) atomicAdd(&yrep[batch_idx[a]], s);
            }
        }
    }
}

extern "C" void kernel_launch(void* const* d_in, const int* in_sizes, int n_in,
                              void* d_out, int out_size, void* d_ws, size_t ws_size,
                              hipStream_t stream) {
    const float* h_energy  = (const float*)d_in[0];
    const float* h_forces  = (const float*)d_in[1];
    const float* V_st      = (const float*)d_in[2];
    const int*   idx_t     = (const int*)d_in[3];
    const int*   batch_idx = (const int*)d_in[4];
    const float* W_energy  = (const float*)d_in[5];
    const float* W_forces  = (const float*)d_in[6];
    const float* b_forces  = (const float*)d_in[7];

    float* ws  = (float*)d_ws;
    float* out = (float*)d_out;

    // Zero replica accumulators (1204096 floats = 301024 f32x4).
    const int zn4 = WS_FLOATS / 4;
    zero_kernel<<<(zn4 + 255) / 256, 256, 0, stream>>>((f32x4*)d_ws, zn4);

    // Fused persistent kernel: 2048 forces + 512 energy blocks.
    fused_kernel<<<FPBLOCKS + EPBLOCKS, 256, 0, stream>>>(
        h_energy, h_forces, V_st, idx_t, batch_idx,
        W_energy, W_forces, b_forces, ws);

    // Merge replicas -> d_out (75250 f32x4 elements).
    merge_kernel<<<(75250 + 255) / 256, 256, 0, stream>>>(ws, out);
}

// Round 12
// 96.766 us; speedup vs baseline: 2.2744x; 1.0270x over previous
//
#include <hip/hip_runtime.h>

#define N_ATOMS 100000
#define N_EDGES 625000
#define N_MOL   1000
#define EMB_ATOM 256
#define EMB_EDGE 128

typedef float f32x4 __attribute__((ext_vector_type(4)));

__device__ __forceinline__ float dot4(f32x4 a, f32x4 b) {
    return a.x * b.x + a.y * b.y + a.z * b.z + a.w * b.w;
}

// ---- workspace layout (floats) ----
// rep_y : 8 replicas x 1024   at ws[0 .. 8192)
// rep_f : 8 replicas x 300000 at ws[8192 .. 2408192)
#define REP      8
#define YREP_STR 1024
#define FREP_OFF 8192
#define FREP_STR 300000
#define WS_FLOATS (FREP_OFF + REP * FREP_STR)    // 2408192 (= 602048 f32x4)

// Zero the replica accumulators (not d_out - merge overwrites d_out fully).
__global__ __launch_bounds__(256) void zero_kernel(f32x4* __restrict__ p, int n4)
{
    const int i = blockIdx.x * blockDim.x + threadIdx.x;
    if (i < n4) p[i] = (f32x4)(0.f, 0.f, 0.f, 0.f);
}

// Merge replicas into d_out. f32x4 elements 0..249 are y (1000 floats),
// 250..75249 are force (300000 floats).
__global__ __launch_bounds__(256) void merge_kernel(
    const float* __restrict__ ws, float* __restrict__ out)
{
    const int i = blockIdx.x * blockDim.x + threadIdx.x;
    if (i >= 250 + 75000) return;
    const f32x4* w4 = reinterpret_cast<const f32x4*>(ws);
    f32x4*       o4 = reinterpret_cast<f32x4*>(out);
    if (i < 250) {
        f32x4 s = (f32x4)(0.f, 0.f, 0.f, 0.f);
        #pragma unroll
        for (int k = 0; k < REP; ++k) s += w4[i + k * (YREP_STR/4)];
        o4[i] = s;
    } else {
        const int j = i - 250;               // force f32x4 index
        const f32x4* f4 = w4 + FREP_OFF/4;
        f32x4 s = (f32x4)(0.f, 0.f, 0.f, 0.f);
        #pragma unroll
        for (int k = 0; k < REP; ++k) s += f4[j + k * (FREP_STR/4)];
        o4[i] = s;
    }
}

// Fused persistent kernel (R11 structure, rebalanced to traffic ratio).
// Blocks [0, FPBLOCKS): forces, grid-stride over 16-edge tiles (8 lanes per
// edge, 2 groups, 128B/thread in flight). Blocks [FPBLOCKS, +EPBLOCKS):
// energy, grid-stride over 8-atom tiles (16 lanes/atom, 2 groups).
// Atomics go to replica (wslot & 7) in ws.
// Per-slot bytes: forces 39063*8448B/7840 = 42.1KB; energy 12500*8256B/2400
// = 43.0KB -> balanced tails.
#define FTILES  ((N_EDGES + 15) / 16)            // 39063
#define FPBLOCKS 1960                            // 7840 wave-slots
#define ETILES  (N_ATOMS / 8)                    // 12500 exact
#define EPBLOCKS 600                             // 2400 wave-slots

__global__ __launch_bounds__(256) void fused_kernel(
    const float* __restrict__ h_energy,
    const float* __restrict__ h_forces,
    const float* __restrict__ V_st,
    const int*   __restrict__ idx_t,
    const int*   __restrict__ batch_idx,
    const float* __restrict__ W_energy,
    const float* __restrict__ W_forces,
    const float* __restrict__ b_forces,
    float*       __restrict__ ws)
{
    const int lane = threadIdx.x & 63;

    if (blockIdx.x < FPBLOCKS) {
        // ---------------- forces ----------------
        const int wslot = blockIdx.x * 4 + (threadIdx.x >> 6);
        const int slot  = lane >> 3;     // 0..7 : edge slot
        const int sub   = lane & 7;      // 0..7 : position within edge row

        const f32x4* wf   = reinterpret_cast<const f32x4*>(W_forces);
        const f32x4* base = reinterpret_cast<const f32x4*>(h_forces); // row = 32 f32x4
        float* frep = ws + FREP_OFF + (wslot & (REP-1)) * FREP_STR;

        f32x4 b0 = wf[sub + 0];
        f32x4 b1 = wf[sub + 8];
        f32x4 b2 = wf[sub + 16];
        f32x4 b3 = wf[sub + 24];
        const float bias = b_forces[0];

        for (int tile = wslot; tile < FTILES; tile += FPBLOCKS * 4) {
            #pragma unroll
            for (int g = 0; g < 2; ++g) {
                const int e = tile * 16 + g * 8 + slot;
                float s = 0.f;
                if (e < N_EDGES) {
                    const f32x4* row = base + (size_t)e * 32;
                    f32x4 a0 = __builtin_nontemporal_load(row + sub + 0);
                    f32x4 a1 = __builtin_nontemporal_load(row + sub + 8);
                    f32x4 a2 = __builtin_nontemporal_load(row + sub + 16);
                    f32x4 a3 = __builtin_nontemporal_load(row + sub + 24);
                    s = dot4(a0, b0) + dot4(a1, b1) + dot4(a2, b2) + dot4(a3, b3);
                }
                s += __shfl_xor(s, 1, 64);
                s += __shfl_xor(s, 2, 64);
                s += __shfl_xor(s, 4, 64);
                if (e < N_EDGES && sub < 3) {
                    const int   t = idx_t[e];
                    const float v = V_st[(size_t)e * 3 + sub];
                    atomicAdd(&frep[(size_t)t * 3 + sub], (s + bias) * v);
                }
            }
        }
    } else if (blockIdx.x < FPBLOCKS + EPBLOCKS) {
        // ---------------- energy ----------------
        const int wslot = (blockIdx.x - FPBLOCKS) * 4 + (threadIdx.x >> 6);
        const int slot  = lane >> 4;     // 0..3 : atom slot
        const int sub   = lane & 15;     // 0..15: position within atom row

        const f32x4* we   = reinterpret_cast<const f32x4*>(W_energy);
        const f32x4* base = reinterpret_cast<const f32x4*>(h_energy); // row = 64 f32x4
        float* yrep = ws + (wslot & (REP-1)) * YREP_STR;

        f32x4 b0 = we[sub + 0];
        f32x4 b1 = we[sub + 16];
        f32x4 b2 = we[sub + 32];
        f32x4 b3 = we[sub + 48];

        for (int tile = wslot; tile < ETILES; tile += EPBLOCKS * 4) {
            #pragma unroll
            for (int g = 0; g < 2; ++g) {
                const int a = tile * 8 + g * 4 + slot;   // < 100000 exact
                const f32x4* row = base + (size_t)a * 64;
                f32x4 a0 = __builtin_nontemporal_load(row + sub + 0);
                f32x4 a1 = __builtin_nontemporal_load(row + sub + 16);
                f32x4 a2 = __builtin_nontemporal_load(row + sub + 32);
                f32x4 a3 = __builtin_nontemporal_load(row + sub + 48);
                float s = dot4(a0, b0) + dot4(a1, b1) + dot4(a2, b2) + dot4(a3, b3);

                s += __shfl_xor(s, 1, 64);
                s += __shfl_xor(s, 2, 64);
                s += __shfl_xor(s, 4, 64);
                s += __shfl_xor(s, 8, 64);

                if (sub == 0) atomicAdd(&yrep[batch_idx[a]], s);
            }
        }
    }
}

extern "C" void kernel_launch(void* const* d_in, const int* in_sizes, int n_in,
                              void* d_out, int out_size, void* d_ws, size_t ws_size,
                              hipStream_t stream) {
    const float* h_energy  = (const float*)d_in[0];
    const float* h_forces  = (const float*)d_in[1];
    const float* V_st      = (const float*)d_in[2];
    const int*   idx_t     = (const int*)d_in[3];
    const int*   batch_idx = (const int*)d_in[4];
    const float* W_energy  = (const float*)d_in[5];
    const float* W_forces  = (const float*)d_in[6];
    const float* b_forces  = (const float*)d_in[7];

    float* ws  = (float*)d_ws;
    float* out = (float*)d_out;

    // Zero replica accumulators (2408192 floats = 602048 f32x4 = 9.6 MB).
    const int zn4 = WS_FLOATS / 4;
    zero_kernel<<<(zn4 + 255) / 256, 256, 0, stream>>>((f32x4*)d_ws, zn4);

    // Fused persistent kernel: 1960 forces + 600 energy blocks (10/CU).
    fused_kernel<<<FPBLOCKS + EPBLOCKS, 256, 0, stream>>>(
        h_energy, h_forces, V_st, idx_t, batch_idx,
        W_energy, W_forces, b_forces, ws);

    // Merge replicas -> d_out (75250 f32x4 elements).
    merge_kernel<<<(75250 + 255) / 256, 256, 0, stream>>>(ws, out);
}

// Round 13
// 95.963 us; speedup vs baseline: 2.2934x; 1.0084x over previous
//
#include <hip/hip_runtime.h>

#define N_ATOMS 100000
#define N_EDGES 625000
#define N_MOL   1000
#define EMB_ATOM 256
#define EMB_EDGE 128

typedef float f32x4 __attribute__((ext_vector_type(4)));

__device__ __forceinline__ float dot4(f32x4 a, f32x4 b) {
    return a.x * b.x + a.y * b.y + a.z * b.z + a.w * b.w;
}

// ---- workspace layout (floats) ----
// rep_y : 8 replicas x 1024   at ws[0 .. 8192)
// rep_f : 8 replicas x 300000 at ws[8192 .. 2408192)
#define REP      8
#define YREP_STR 1024
#define FREP_OFF 8192
#define FREP_STR 300000
#define WS_FLOATS (FREP_OFF + REP * FREP_STR)    // 2408192 (= 602048 f32x4)

__global__ __launch_bounds__(256) void zero_kernel(f32x4* __restrict__ p, int n4)
{
    const int i = blockIdx.x * blockDim.x + threadIdx.x;
    if (i < n4) p[i] = (f32x4)(0.f, 0.f, 0.f, 0.f);
}

// Merge replicas into d_out. f32x4 elements 0..249 are y (1000 floats),
// 250..75249 are force (300000 floats).
__global__ __launch_bounds__(256) void merge_kernel(
    const float* __restrict__ ws, float* __restrict__ out)
{
    const int i = blockIdx.x * blockDim.x + threadIdx.x;
    if (i >= 250 + 75000) return;
    const f32x4* w4 = reinterpret_cast<const f32x4*>(ws);
    f32x4*       o4 = reinterpret_cast<f32x4*>(out);
    if (i < 250) {
        f32x4 s = (f32x4)(0.f, 0.f, 0.f, 0.f);
        #pragma unroll
        for (int k = 0; k < REP; ++k) s += w4[i + k * (YREP_STR/4)];
        o4[i] = s;
    } else {
        const int j = i - 250;
        const f32x4* f4 = w4 + FREP_OFF/4;
        f32x4 s = (f32x4)(0.f, 0.f, 0.f, 0.f);
        #pragma unroll
        for (int k = 0; k < REP; ++k) s += f4[j + k * (FREP_STR/4)];
        o4[i] = s;
    }
}

// Fused persistent kernel, software-pipelined: tile t+1's loads are issued
// BEFORE tile t's atomics, so the (in-order) vmcnt retirement of the next
// data-wait never gates on an atomic issued this iteration. Atomics get a
// full iteration (~8k cyc) of slack to complete.
#define FTILES   ((N_EDGES + 15) / 16)           // 39063
#define FPBLOCKS 1960                            // 7840 wave-slots
#define FSTRIDE  (FPBLOCKS * 4)
#define ETILES   (N_ATOMS / 8)                   // 12500 exact
#define EPBLOCKS 600                             // 2400 wave-slots
#define ESTRIDE  (EPBLOCKS * 4)

__global__ __launch_bounds__(256) void fused_kernel(
    const float* __restrict__ h_energy,
    const float* __restrict__ h_forces,
    const float* __restrict__ V_st,
    const int*   __restrict__ idx_t,
    const int*   __restrict__ batch_idx,
    const float* __restrict__ W_energy,
    const float* __restrict__ W_forces,
    const float* __restrict__ b_forces,
    float*       __restrict__ ws)
{
    const int lane = threadIdx.x & 63;

    if (blockIdx.x < FPBLOCKS) {
        // ---------------- forces ----------------
        const int wslot = blockIdx.x * 4 + (threadIdx.x >> 6);
        const int slot  = lane >> 3;     // 0..7 : edge slot
        const int sub   = lane & 7;      // 0..7 : position within edge row

        const f32x4* wf   = reinterpret_cast<const f32x4*>(W_forces);
        const f32x4* base = reinterpret_cast<const f32x4*>(h_forces); // row = 32 f32x4
        float* frep = ws + FREP_OFF + (wslot & (REP-1)) * FREP_STR;

        f32x4 b0 = wf[sub + 0];
        f32x4 b1 = wf[sub + 8];
        f32x4 b2 = wf[sub + 16];
        f32x4 b3 = wf[sub + 24];
        const float bias = b_forces[0];

        // pipeline registers: current tile (c*, ct, cv, cok)
        f32x4 c[8]; int ct[2]; float cv[2]; bool cok[2];

        // prologue: issue loads for first tile (every slot has >=4 tiles)
        int tile = wslot;
        {
            #pragma unroll
            for (int g = 0; g < 2; ++g) {
                const int e  = tile * 16 + g * 8 + slot;
                cok[g] = (e < N_EDGES);
                const int ec = cok[g] ? e : (N_EDGES - 1);
                const f32x4* row = base + (size_t)ec * 32;
                c[g*4+0] = __builtin_nontemporal_load(row + sub + 0);
                c[g*4+1] = __builtin_nontemporal_load(row + sub + 8);
                c[g*4+2] = __builtin_nontemporal_load(row + sub + 16);
                c[g*4+3] = __builtin_nontemporal_load(row + sub + 24);
                ct[g] = idx_t[ec];
                cv[g] = V_st[(size_t)ec * 3 + (sub < 3 ? sub : 0)];
            }
        }

        for (;;) {
            const int next     = tile + FSTRIDE;
            const bool has_next = (next < FTILES);

            f32x4 n[8]; int nt[2]; float nv[2]; bool nok[2];
            if (has_next) {
                // issue next tile's loads BEFORE current tile's atomics
                #pragma unroll
                for (int g = 0; g < 2; ++g) {
                    const int e  = next * 16 + g * 8 + slot;
                    nok[g] = (e < N_EDGES);
                    const int ec = nok[g] ? e : (N_EDGES - 1);
                    const f32x4* row = base + (size_t)ec * 32;
                    n[g*4+0] = __builtin_nontemporal_load(row + sub + 0);
                    n[g*4+1] = __builtin_nontemporal_load(row + sub + 8);
                    n[g*4+2] = __builtin_nontemporal_load(row + sub + 16);
                    n[g*4+3] = __builtin_nontemporal_load(row + sub + 24);
                    nt[g] = idx_t[ec];
                    nv[g] = V_st[(size_t)ec * 3 + (sub < 3 ? sub : 0)];
                }
            }

            // compute + scatter current tile
            #pragma unroll
            for (int g = 0; g < 2; ++g) {
                float s = dot4(c[g*4+0], b0) + dot4(c[g*4+1], b1)
                        + dot4(c[g*4+2], b2) + dot4(c[g*4+3], b3);
                s += __shfl_xor(s, 1, 64);
                s += __shfl_xor(s, 2, 64);
                s += __shfl_xor(s, 4, 64);
                if (cok[g] && sub < 3)
                    atomicAdd(&frep[(size_t)ct[g] * 3 + sub], (s + bias) * cv[g]);
            }

            if (!has_next) break;
            #pragma unroll
            for (int k = 0; k < 8; ++k) c[k] = n[k];
            #pragma unroll
            for (int g = 0; g < 2; ++g) { ct[g] = nt[g]; cv[g] = nv[g]; cok[g] = nok[g]; }
            tile = next;
        }
    } else if (blockIdx.x < FPBLOCKS + EPBLOCKS) {
        // ---------------- energy ----------------
        const int wslot = (blockIdx.x - FPBLOCKS) * 4 + (threadIdx.x >> 6);
        const int slot  = lane >> 4;     // 0..3 : atom slot
        const int sub   = lane & 15;     // 0..15: position within atom row

        const f32x4* we   = reinterpret_cast<const f32x4*>(W_energy);
        const f32x4* base = reinterpret_cast<const f32x4*>(h_energy); // row = 64 f32x4
        float* yrep = ws + (wslot & (REP-1)) * YREP_STR;

        f32x4 b0 = we[sub + 0];
        f32x4 b1 = we[sub + 16];
        f32x4 b2 = we[sub + 32];
        f32x4 b3 = we[sub + 48];

        f32x4 c[8]; int cm[2];

        int tile = wslot;   // every slot has >=5 tiles (12500/2400)
        {
            #pragma unroll
            for (int g = 0; g < 2; ++g) {
                const int a = tile * 8 + g * 4 + slot;      // always < 100000
                const f32x4* row = base + (size_t)a * 64;
                c[g*4+0] = __builtin_nontemporal_load(row + sub + 0);
                c[g*4+1] = __builtin_nontemporal_load(row + sub + 16);
                c[g*4+2] = __builtin_nontemporal_load(row + sub + 32);
                c[g*4+3] = __builtin_nontemporal_load(row + sub + 48);
                cm[g] = batch_idx[a];
            }
        }

        for (;;) {
            const int next      = tile + ESTRIDE;
            const bool has_next = (next < ETILES);

            f32x4 n[8]; int nm[2];
            if (has_next) {
                #pragma unroll
                for (int g = 0; g < 2; ++g) {
                    const int a = next * 8 + g * 4 + slot;
                    const f32x4* row = base + (size_t)a * 64;
                    n[g*4+0] = __builtin_nontemporal_load(row + sub + 0);
                    n[g*4+1] = __builtin_nontemporal_load(row + sub + 16);
                    n[g*4+2] = __builtin_nontemporal_load(row + sub + 32);
                    n[g*4+3] = __builtin_nontemporal_load(row + sub + 48);
                    nm[g] = batch_idx[a];
                }
            }

            #pragma unroll
            for (int g = 0; g < 2; ++g) {
                float s = dot4(c[g*4+0], b0) + dot4(c[g*4+1], b1)
                        + dot4(c[g*4+2], b2) + dot4(c[g*4+3], b3);
                s += __shfl_xor(s, 1, 64);
                s += __shfl_xor(s, 2, 64);
                s += __shfl_xor(s, 4, 64);
                s += __shfl_xor(s, 8, 64);
                if (sub == 0) atomicAdd(&yrep[cm[g]], s);
            }

            if (!has_next) break;
            #pragma unroll
            for (int k = 0; k < 8; ++k) c[k] = n[k];
            cm[0] = nm[0]; cm[1] = nm[1];
            tile = next;
        }
    }
}

extern "C" void kernel_launch(void* const* d_in, const int* in_sizes, int n_in,
                              void* d_out, int out_size, void* d_ws, size_t ws_size,
                              hipStream_t stream) {
    const float* h_energy  = (const float*)d_in[0];
    const float* h_forces  = (const float*)d_in[1];
    const float* V_st      = (const float*)d_in[2];
    const int*   idx_t     = (const int*)d_in[3];
    const int*   batch_idx = (const int*)d_in[4];
    const float* W_energy  = (const float*)d_in[5];
    const float* W_forces  = (const float*)d_in[6];
    const float* b_forces  = (const float*)d_in[7];

    float* ws  = (float*)d_ws;
    float* out = (float*)d_out;

    // Zero replica accumulators (2408192 floats = 602048 f32x4 = 9.6 MB).
    const int zn4 = WS_FLOATS / 4;
    zero_kernel<<<(zn4 + 255) / 256, 256, 0, stream>>>((f32x4*)d_ws, zn4);

    // Fused persistent pipelined kernel: 1960 forces + 600 energy blocks.
    fused_kernel<<<FPBLOCKS + EPBLOCKS, 256, 0, stream>>>(
        h_energy, h_forces, V_st, idx_t, batch_idx,
        W_energy, W_forces, b_forces, ws);

    // Merge replicas -> d_out (75250 f32x4 elements).
    merge_kernel<<<(75250 + 255) / 256, 256, 0, stream>>>(ws, out);
}